// Round 7
// baseline (341.547 us; speedup 1.0000x reference)
//
#include <hip/hip_runtime.h>

// GCN: 3 x (gather-aggregate via CSR -> GEMM(+bias,+relu))
// R1: CSR gather aggregation (no fp32 atomics).
// R2: layers 1&2 GEMM -> bf16 MFMA, global_load_lds(16) staging, XOR swizzle.
// R3: bf16 end-to-end; layer-3 GEMM -> bf16 MFMA; fused epilogues.
// R4: double-buffered LDS in MFMA GEMMs; XCD-partitioned gather.
// R5: XCD grid swizzle -> REGRESSED (43->49.6us despite FETCH 89->19MB):
//     GEMM is latency/occupancy-bound, not fetch-bound. Reverted.
// R6: BN 128->64 -> 1264 blocks (~5/CU, was 2.47); triple-buffer LDS with
//     raw `s_waitcnt vmcnt(3); s_barrier` (never vmcnt(0) in the K-loop --
//     prefetch distance 2 stays in flight across the barrier).
constexpr int NN   = 10000;
constexpr int NE   = 160000;
constexpr int F    = 1024;
constexpr int C3   = 64;
constexpr int MPAD = 10112;   // 79 * 128

typedef __attribute__((ext_vector_type(8))) short short8;
typedef __attribute__((ext_vector_type(8))) unsigned short ushort8v;
typedef __attribute__((ext_vector_type(4))) float floatx4;

__device__ __forceinline__ unsigned short f2bf(float f) {
    union { float f; unsigned u; } v; v.f = f;
    unsigned r = v.u + 0x7fff + ((v.u >> 16) & 1);   // RNE
    return (unsigned short)(r >> 16);
}
__device__ __forceinline__ float bf2f(unsigned short u) {
    union { unsigned u; float f; } v; v.u = ((unsigned)u) << 16;
    return v.f;
}

__device__ __forceinline__ void gl_lds16(const void* g, void* l) {
    __builtin_amdgcn_global_load_lds(
        (const __attribute__((address_space(1))) unsigned int*)g,
        (__attribute__((address_space(3))) unsigned int*)l, 16, 0, 0);
}

// ---- CSR build ------------------------------------------------------------

__global__ __launch_bounds__(256) void k_degree(const int* __restrict__ src,
                                                const int* __restrict__ dst,
                                                int* __restrict__ deg_out,
                                                int* __restrict__ deg_in) {
    int e = blockIdx.x * 256 + threadIdx.x;
    if (e < NE) {
        atomicAdd(&deg_out[src[e]], 1);
        atomicAdd(&deg_in[dst[e]], 1);
    }
}

__global__ __launch_bounds__(256) void k_norm(const int* __restrict__ deg_out,
                                              const int* __restrict__ deg_in,
                                              float* __restrict__ norm_src,
                                              float* __restrict__ norm_dst) {
    int v = blockIdx.x * 256 + threadIdx.x;
    if (v < MPAD) {
        norm_src[v] = rsqrtf(fmaxf((float)deg_out[v], 1.0f));
        norm_dst[v] = rsqrtf(fmaxf((float)deg_in[v], 1.0f));
    }
}

__global__ __launch_bounds__(1024) void k_scan(const int* __restrict__ deg_in,
                                               int* __restrict__ row_ptr,
                                               int* __restrict__ cursor) {
    constexpr int CH = 10;
    __shared__ int sums[1024];
    const int tid = threadIdx.x;
    int local[CH];
    int tsum = 0;
#pragma unroll
    for (int j = 0; j < CH; ++j) {
        int idx = tid * CH + j;
        int v = (idx < NN) ? deg_in[idx] : 0;
        local[j] = v;
        tsum += v;
    }
    sums[tid] = tsum;
    __syncthreads();
    for (int off = 1; off < 1024; off <<= 1) {
        int v = (tid >= off) ? sums[tid - off] : 0;
        __syncthreads();
        sums[tid] += v;
        __syncthreads();
    }
    int run = sums[tid] - tsum;
#pragma unroll
    for (int j = 0; j < CH; ++j) {
        int idx = tid * CH + j;
        if (idx < NN) {
            row_ptr[idx] = run;
            cursor[idx]  = run;
        }
        run += local[j];
    }
    if (tid == 1023) row_ptr[NN] = sums[1023];
}

__global__ __launch_bounds__(256) void k_bucket(const int* __restrict__ src,
                                                const int* __restrict__ dst,
                                                int* __restrict__ cursor,
                                                int* __restrict__ csr_src) {
    int e = blockIdx.x * 256 + threadIdx.x;
    if (e < NE) {
        int slot = atomicAdd(&cursor[dst[e]], 1);
        csr_src[slot] = src[e];
    }
}

// ---- weight transpose+convert: W[k][n] fp32 -> Wt[n][k] bf16 (k dim = F) --

__global__ __launch_bounds__(256) void k_wconv(const float* __restrict__ W,
                                               unsigned short* __restrict__ Wt,
                                               int N) {
    __shared__ float tile[32][33];
    const int n0 = blockIdx.x * 32, k0 = blockIdx.y * 32;
    const int tx = threadIdx.x & 31, ty = threadIdx.x >> 5;   // 32 x 8
#pragma unroll
    for (int i = 0; i < 32; i += 8)
        tile[ty + i][tx] = W[(size_t)(k0 + ty + i) * N + n0 + tx];  // [k][n]
    __syncthreads();
#pragma unroll
    for (int i = 0; i < 32; i += 8)
        Wt[(size_t)(n0 + ty + i) * F + k0 + tx] = f2bf(tile[tx][ty + i]);
}

// ---- h -> bf16 with norm_src fold: hb[v][f] = bf16(ns[v]*h[v][f]) ---------

__global__ __launch_bounds__(256) void k_hcvt(const float* __restrict__ h,
                                              const float* __restrict__ norm_src,
                                              unsigned short* __restrict__ hb) {
    int idx = blockIdx.x * 256 + threadIdx.x;     // NN*128 total
    int v = idx >> 7, f8 = (idx & 127) * 8;
    float ns = norm_src[v];
    const float4 a = *(const float4*)(h + (size_t)v * F + f8);
    const float4 b = *(const float4*)(h + (size_t)v * F + f8 + 4);
    ushort8v o;
    o[0] = f2bf(ns * a.x); o[1] = f2bf(ns * a.y);
    o[2] = f2bf(ns * a.z); o[3] = f2bf(ns * a.w);
    o[4] = f2bf(ns * b.x); o[5] = f2bf(ns * b.y);
    o[6] = f2bf(ns * b.z); o[7] = f2bf(ns * b.w);
    *(ushort8v*)(hb + (size_t)v * F + f8) = o;
}

// ---- aggregation: bf16 in, fp32 accumulate, bf16 out ----------------------
// XCD-partitioned: chunk c = blockIdx%8 (rides round-robin block->XCD map),
// 128 feats per chunk -> per-XCD slice 10000*128*2B = 2.56 MB < 4 MB L2.
// 16 nodes per block, 16 lanes x 8 bf16 (16B) per node. Edge loop unroll x2.
__global__ __launch_bounds__(256) void k_aggb(const unsigned short* __restrict__ xb,
                                              const int* __restrict__ row_ptr,
                                              const int* __restrict__ csr_src,
                                              unsigned short* __restrict__ aggb) {
    const int c = blockIdx.x & 7;                       // feature chunk -> XCD
    const int g = blockIdx.x >> 3;                      // node group
    const int v = g * 16 + (threadIdx.x >> 4);          // 625*16 == NN exactly
    const int f8 = c * 128 + (threadIdx.x & 15) * 8;
    const int lo = row_ptr[v], hi = row_ptr[v + 1];
    float acc[8] = {0.f, 0.f, 0.f, 0.f, 0.f, 0.f, 0.f, 0.f};
    int i = lo;
    for (; i + 2 <= hi; i += 2) {
        int s0 = csr_src[i], s1 = csr_src[i + 1];
        ushort8v x0 = *(const ushort8v*)(xb + (size_t)s0 * F + f8);
        ushort8v x1 = *(const ushort8v*)(xb + (size_t)s1 * F + f8);
#pragma unroll
        for (int j = 0; j < 8; ++j) acc[j] += bf2f(x0[j]);
#pragma unroll
        for (int j = 0; j < 8; ++j) acc[j] += bf2f(x1[j]);
    }
    if (i < hi) {
        int s = csr_src[i];
        ushort8v xv = *(const ushort8v*)(xb + (size_t)s * F + f8);
#pragma unroll
        for (int j = 0; j < 8; ++j) acc[j] += bf2f(xv[j]);
    }
    ushort8v o;
#pragma unroll
    for (int j = 0; j < 8; ++j) o[j] = f2bf(acc[j]);
    *(ushort8v*)(aggb + (size_t)v * F + f8) = o;
}

// layer-3 aggregation over z3 (fp32, 64 feats), fused nd/bias, writes d_out.
// 16 nodes per block, 16 lanes x float4 per node.
__global__ __launch_bounds__(256) void k_agg64(const float* __restrict__ z,
                                               const int* __restrict__ row_ptr,
                                               const int* __restrict__ csr_src,
                                               const float* __restrict__ norm_dst,
                                               const float* __restrict__ b3,
                                               float* __restrict__ out) {
    const int v = blockIdx.x * 16 + (threadIdx.x >> 4);
    if (v >= NN) return;
    const int f4 = (threadIdx.x & 15) * 4;
    const int lo = row_ptr[v], hi = row_ptr[v + 1];
    float4 acc = {0.f, 0.f, 0.f, 0.f};
    for (int i = lo; i < hi; ++i) {
        int s = csr_src[i];
        float4 zv = *(const float4*)(z + (size_t)s * C3 + f4);
        acc.x += zv.x; acc.y += zv.y; acc.z += zv.z; acc.w += zv.w;
    }
    float nd = norm_dst[v];
    float4 bv = *(const float4*)(b3 + f4);
    float4 o;
    o.x = acc.x * nd + bv.x; o.y = acc.y * nd + bv.y;
    o.z = acc.z * nd + bv.z; o.w = acc.w * nd + bv.w;
    *(float4*)(out + (size_t)v * C3 + f4) = o;
}

// ---- bf16 MFMA GEMM, layers 1&2: 128x64 tile, triple-buffer, raw barrier --
// Cb[m][n] = bf16( rs2[m] * relu( rs1[m]*(A@Bt^T)[m,n] + bias[n] ) )
// A: [MPAD][F] bf16. Bt: [F n][F k] bf16. Grid (79,16)=1264 blocks (~5/CU).
// 4 waves: wave computes 64x32 (mb 0..3, nb 0..1).
// K-loop: prefetch distance 2, `s_waitcnt vmcnt(3); s_barrier` keeps the
// newest tile's 3 loads in flight across the barrier (never vmcnt(0)).
__global__ __launch_bounds__(256) void k_gemm_bf16(
        const unsigned short* __restrict__ A,
        const unsigned short* __restrict__ Bt,
        const float* __restrict__ bias,
        const float* __restrict__ rs1,   // norm_dst (pre-bias)
        const float* __restrict__ rs2,   // norm_src (post-relu)
        unsigned short* __restrict__ Cb) {
    constexpr int NT = F / 32;           // 32 K-tiles
    __shared__ short As[3][128 * 32];
    __shared__ short Bs[3][64 * 32];
    const int t = threadIdx.x, lane = t & 63, wid = t >> 6;
    const int m0 = blockIdx.x * 128, n0 = blockIdx.y * 64;
    const int wm0 = (wid & 1) * 64, wn0 = (wid >> 1) * 32;
    const int lr = lane & 15, q = lane >> 4;

    // staging: A instrs {wid, wid+4} (16 rows each), B instr {wid}.
    const int rA0 = wid * 16 + (lane >> 2);
    const int rA1 = (wid + 4) * 16 + (lane >> 2);
    const int rB  = wid * 16 + (lane >> 2);
    const int sA0 = (((lane & 3) ^ ((rA0 >> 1) & 3)) * 8);
    const int sA1 = (((lane & 3) ^ ((rA1 >> 1) & 3)) * 8);
    const int sB  = (((lane & 3) ^ ((rB  >> 1) & 3)) * 8);
    const unsigned short* aSrc0 = A  + (size_t)(m0 + rA0) * F + sA0;
    const unsigned short* aSrc1 = A  + (size_t)(m0 + rA1) * F + sA1;
    const unsigned short* bSrc  = Bt + (size_t)(n0 + rB)  * F + sB;
    short* aDst0 = &As[0][(wid)     * 512];
    short* aDst1 = &As[0][(wid + 4) * 512];
    short* bDst  = &Bs[0][(wid)     * 512];

    // ds_read fragment base pointers (buffer 0)
    const short* ap[4];
    const short* bp[2];
#pragma unroll
    for (int mb = 0; mb < 4; ++mb) {
        int m = wm0 + mb * 16 + lr;
        ap[mb] = &As[0][m * 32 + (q ^ ((m >> 1) & 3)) * 8];
    }
#pragma unroll
    for (int nb = 0; nb < 2; ++nb) {
        int n = wn0 + nb * 16 + lr;
        bp[nb] = &Bs[0][n * 32 + (q ^ ((n >> 1) & 3)) * 8];
    }

    floatx4 acc[4][2] = {};

    // prologue: stage tiles 0,1 into bufs 0,1 (6 loads in flight / thread)
    gl_lds16(aSrc0,      aDst0);
    gl_lds16(aSrc1,      aDst1);
    gl_lds16(bSrc,       bDst);
    gl_lds16(aSrc0 + 32, aDst0 + 4096);
    gl_lds16(aSrc1 + 32, aDst1 + 4096);
    gl_lds16(bSrc  + 32, bDst  + 2048);

    for (int kt = 0; kt < NT; ++kt) {
        if (kt < NT - 1) {
            // oldest tile's 3 loads done; newest tile's 3 stay in flight
            asm volatile("s_waitcnt vmcnt(3)\n\ts_barrier" ::: "memory");
        } else {
            asm volatile("s_waitcnt vmcnt(0)\n\ts_barrier" ::: "memory");
        }
        if (kt + 2 < NT) {
            const int pb = (kt + 2) % 3;
            const int k0 = (kt + 2) * 32;
            gl_lds16(aSrc0 + k0, aDst0 + pb * 4096);
            gl_lds16(aSrc1 + k0, aDst1 + pb * 4096);
            gl_lds16(bSrc  + k0, bDst  + pb * 2048);
        }
        const int ba = (kt % 3) * 4096;
        const int bb = (kt % 3) * 2048;
        short8 af[4], bf[2];
#pragma unroll
        for (int mb = 0; mb < 4; ++mb) af[mb] = *(const short8*)(ap[mb] + ba);
#pragma unroll
        for (int nb = 0; nb < 2; ++nb) bf[nb] = *(const short8*)(bp[nb] + bb);
#pragma unroll
        for (int mb = 0; mb < 4; ++mb)
#pragma unroll
            for (int nb = 0; nb < 2; ++nb)
                acc[mb][nb] = __builtin_amdgcn_mfma_f32_16x16x32_bf16(
                    af[mb], bf[nb], acc[mb][nb], 0, 0, 0);
    }

    float s1[4][4], s2[4][4];
#pragma unroll
    for (int mb = 0; mb < 4; ++mb)
#pragma unroll
        for (int r = 0; r < 4; ++r) {
            int row = m0 + wm0 + mb * 16 + q * 4 + r;
            s1[mb][r] = rs1[row];
            s2[mb][r] = rs2[row];
        }
#pragma unroll
    for (int nb = 0; nb < 2; ++nb) {
        int col = n0 + wn0 + nb * 16 + lr;
        float bv = bias[col];
#pragma unroll
        for (int mb = 0; mb < 4; ++mb)
#pragma unroll
            for (int r = 0; r < 4; ++r) {
                int row = m0 + wm0 + mb * 16 + q * 4 + r;
                float v = fmaxf(acc[mb][nb][r] * s1[mb][r] + bv, 0.f) * s2[mb][r];
                Cb[(size_t)row * F + col] = f2bf(v);
            }
    }
}

// ---- bf16 MFMA GEMM, layer 3: z3 = x2' @ Wt3^T, fp32 out, N=64, dbuf ------
// BM=64, 4 waves (wave w -> rows w*16..w*16+15, cols 0..63), grid MPAD/64.
__global__ __launch_bounds__(256) void k_gemm3(
        const unsigned short* __restrict__ A,
        const unsigned short* __restrict__ Bt,   // [64 n][F k]
        float* __restrict__ Z) {
    __shared__ short As3[2][64 * 32];
    __shared__ short Bs3[2][64 * 32];
    const int t = threadIdx.x, lane = t & 63, wid = t >> 6;
    const int m0 = blockIdx.x * 64;
    const int lr = lane & 15, q = lane >> 4;

    const int r = wid * 16 + (lane >> 2);
    const int soff = (((lane & 3) ^ ((r >> 1) & 3)) * 8);
    const unsigned short* aSrc = A  + (size_t)(m0 + r) * F + soff;
    const unsigned short* bSrc = Bt + (size_t)r * F + soff;

    const short* ap;
    {
        int m = wid * 16 + lr;
        ap = &As3[0][m * 32 + (q ^ ((m >> 1) & 3)) * 8];
    }
    const short* bp[4];
#pragma unroll
    for (int nb = 0; nb < 4; ++nb) {
        int n = nb * 16 + lr;
        bp[nb] = &Bs3[0][n * 32 + (q ^ ((n >> 1) & 3)) * 8];
    }

    floatx4 acc[4] = {};

    gl_lds16(aSrc, &As3[0][wid * 512]);
    gl_lds16(bSrc, &Bs3[0][wid * 512]);

    for (int kt = 0; kt < F / 32; ++kt) {
        const int buf = kt & 1;
        __syncthreads();
        if (kt + 1 < F / 32) {
            int k0 = (kt + 1) * 32;
            gl_lds16(aSrc + k0, &As3[buf ^ 1][wid * 512]);
            gl_lds16(bSrc + k0, &Bs3[buf ^ 1][wid * 512]);
        }
        const int bo = buf * (64 * 32);
        short8 af = *(const short8*)(ap + bo);
        short8 bf[4];
#pragma unroll
        for (int nb = 0; nb < 4; ++nb) bf[nb] = *(const short8*)(bp[nb] + bo);
#pragma unroll
        for (int nb = 0; nb < 4; ++nb)
            acc[nb] = __builtin_amdgcn_mfma_f32_16x16x32_bf16(af, bf[nb], acc[nb], 0, 0, 0);
    }

#pragma unroll
    for (int nb = 0; nb < 4; ++nb) {
        int col = nb * 16 + lr;
#pragma unroll
        for (int ri = 0; ri < 4; ++ri) {
            int row = m0 + wid * 16 + q * 4 + ri;
            Z[(size_t)row * C3 + col] = acc[nb][ri];
        }
    }
}

// ---- driver ---------------------------------------------------------------

extern "C" void kernel_launch(void* const* d_in, const int* in_sizes, int n_in,
                              void* d_out, int out_size, void* d_ws, size_t ws_size,
                              hipStream_t stream) {
    const float* h   = (const float*)d_in[0];
    const int*   src = (const int*)d_in[1];
    const int*   dst = (const int*)d_in[2];
    const float* W1  = (const float*)d_in[3];
    const float* b1  = (const float*)d_in[4];
    const float* W2  = (const float*)d_in[5];
    const float* b2  = (const float*)d_in[6];
    const float* W3  = (const float*)d_in[7];
    const float* b3  = (const float*)d_in[8];
    float* out = (float*)d_out;

    char* ws = (char*)d_ws;
    int*   deg_out  = (int*)ws;                       ws += MPAD * 4;
    int*   deg_in   = (int*)ws;                       ws += MPAD * 4;
    float* norm_src = (float*)ws;                     ws += MPAD * 4;
    float* norm_dst = (float*)ws;                     ws += MPAD * 4;
    int*   row_ptr  = (int*)ws;                       ws += (NN + 1) * 4;
    int*   cursor   = (int*)ws;                       ws += NN * 4;
    int*   csr_src  = (int*)ws;                       ws += NE * 4;
    ws = (char*)(((size_t)ws + 255) & ~(size_t)255);
    unsigned short* hb   = (unsigned short*)ws;       ws += (size_t)MPAD * F * 2;
    unsigned short* aggb = (unsigned short*)ws;       ws += (size_t)MPAD * F * 2;
    unsigned short* xb   = (unsigned short*)ws;       ws += (size_t)MPAD * F * 2;
    unsigned short* Wt1  = (unsigned short*)ws;       ws += (size_t)F * F * 2;
    unsigned short* Wt2  = (unsigned short*)ws;       ws += (size_t)F * F * 2;
    unsigned short* Wt3  = (unsigned short*)ws;       ws += (size_t)C3 * F * 2;
    float* z3       = (float*)ws;                     // MPAD * C3 * 4

    // CSR build + norms + weight conversion + h conversion
    hipMemsetAsync(deg_out, 0, 2 * MPAD * sizeof(int), stream);
    k_degree<<<(NE + 255) / 256, 256, 0, stream>>>(src, dst, deg_out, deg_in);
    k_norm<<<(MPAD + 255) / 256, 256, 0, stream>>>(deg_out, deg_in, norm_src, norm_dst);
    k_scan<<<1, 1024, 0, stream>>>(deg_in, row_ptr, cursor);
    k_bucket<<<(NE + 255) / 256, 256, 0, stream>>>(src, dst, cursor, csr_src);
    k_wconv<<<dim3(F / 32, F / 32), 256, 0, stream>>>(W1, Wt1, F);
    k_wconv<<<dim3(F / 32, F / 32), 256, 0, stream>>>(W2, Wt2, F);
    k_wconv<<<dim3(C3 / 32, F / 32), 256, 0, stream>>>(W3, Wt3, C3);
    k_hcvt<<<NN * 128 / 256, 256, 0, stream>>>(h, norm_src, hb);

    // layer 1: aggb = Sum hb[src]; xb = bf16(ns.*relu(nd.*(aggb@W1)+b1))
    k_aggb<<<(NN / 16) * 8, 256, 0, stream>>>(hb, row_ptr, csr_src, aggb);
    k_gemm_bf16<<<dim3(MPAD / 128, F / 64), 256, 0, stream>>>(aggb, Wt1, b1, norm_dst, norm_src, xb);

    // layer 2
    k_aggb<<<(NN / 16) * 8, 256, 0, stream>>>(xb, row_ptr, csr_src, aggb);
    k_gemm_bf16<<<dim3(MPAD / 128, F / 64), 256, 0, stream>>>(aggb, Wt2, b2, norm_dst, norm_src, xb);

    // layer 3: z3 = xb @ W3t ; out = nd.*(A z3) + b3
    k_gemm3<<<MPAD / 64, 256, 0, stream>>>(xb, Wt3, z3);
    k_agg64<<<(NN + 15) / 16, 256, 0, stream>>>(z3, row_ptr, csr_src, norm_dst, b3, out);
}

// Round 8
// 304.798 us; speedup vs baseline: 1.1206x; 1.1206x over previous
//
#include <hip/hip_runtime.h>

// GCN: 3 x (gather-aggregate via CSR -> GEMM(+bias,+relu))
// R1: CSR gather aggregation (no fp32 atomics).
// R2: layers 1&2 GEMM -> bf16 MFMA, global_load_lds(16) staging, XOR swizzle.
// R3: bf16 end-to-end; layer-3 GEMM -> bf16 MFMA; fused epilogues.
// R4: double-buffered LDS in MFMA GEMMs; XCD-partitioned gather. (GEMM 43us)
// R5: XCD grid swizzle -> REGRESSED (traffic same, rate dropped). Reverted.
// R6: BN=64 + vmcnt(3) triple-buf -> REGRESSED; time tracked bytes exactly
//     (331->497 MB = 43->66us). GEMM is staging-bytes-bound at ~7.5 TB/s,
//     and that rate is concurrency-limited (24% occupancy).
// R7: 128x128 tile, dbuf (R4 structure) with 512-thread blocks (8 waves,
//     64x32 per wave): same 331 MB staging, 2x waves/CU (9.9 -> 19.8).
constexpr int NN   = 10000;
constexpr int NE   = 160000;
constexpr int F    = 1024;
constexpr int C3   = 64;
constexpr int MPAD = 10112;   // 79 * 128

typedef __attribute__((ext_vector_type(8))) short short8;
typedef __attribute__((ext_vector_type(8))) unsigned short ushort8v;
typedef __attribute__((ext_vector_type(4))) float floatx4;

__device__ __forceinline__ unsigned short f2bf(float f) {
    union { float f; unsigned u; } v; v.f = f;
    unsigned r = v.u + 0x7fff + ((v.u >> 16) & 1);   // RNE
    return (unsigned short)(r >> 16);
}
__device__ __forceinline__ float bf2f(unsigned short u) {
    union { unsigned u; float f; } v; v.u = ((unsigned)u) << 16;
    return v.f;
}

__device__ __forceinline__ void gl_lds16(const void* g, void* l) {
    __builtin_amdgcn_global_load_lds(
        (const __attribute__((address_space(1))) unsigned int*)g,
        (__attribute__((address_space(3))) unsigned int*)l, 16, 0, 0);
}

// ---- CSR build ------------------------------------------------------------

__global__ __launch_bounds__(256) void k_degree(const int* __restrict__ src,
                                                const int* __restrict__ dst,
                                                int* __restrict__ deg_out,
                                                int* __restrict__ deg_in) {
    int e = blockIdx.x * 256 + threadIdx.x;
    if (e < NE) {
        atomicAdd(&deg_out[src[e]], 1);
        atomicAdd(&deg_in[dst[e]], 1);
    }
}

__global__ __launch_bounds__(256) void k_norm(const int* __restrict__ deg_out,
                                              const int* __restrict__ deg_in,
                                              float* __restrict__ norm_src,
                                              float* __restrict__ norm_dst) {
    int v = blockIdx.x * 256 + threadIdx.x;
    if (v < MPAD) {
        norm_src[v] = rsqrtf(fmaxf((float)deg_out[v], 1.0f));
        norm_dst[v] = rsqrtf(fmaxf((float)deg_in[v], 1.0f));
    }
}

__global__ __launch_bounds__(1024) void k_scan(const int* __restrict__ deg_in,
                                               int* __restrict__ row_ptr,
                                               int* __restrict__ cursor) {
    constexpr int CH = 10;
    __shared__ int sums[1024];
    const int tid = threadIdx.x;
    int local[CH];
    int tsum = 0;
#pragma unroll
    for (int j = 0; j < CH; ++j) {
        int idx = tid * CH + j;
        int v = (idx < NN) ? deg_in[idx] : 0;
        local[j] = v;
        tsum += v;
    }
    sums[tid] = tsum;
    __syncthreads();
    for (int off = 1; off < 1024; off <<= 1) {
        int v = (tid >= off) ? sums[tid - off] : 0;
        __syncthreads();
        sums[tid] += v;
        __syncthreads();
    }
    int run = sums[tid] - tsum;
#pragma unroll
    for (int j = 0; j < CH; ++j) {
        int idx = tid * CH + j;
        if (idx < NN) {
            row_ptr[idx] = run;
            cursor[idx]  = run;
        }
        run += local[j];
    }
    if (tid == 1023) row_ptr[NN] = sums[1023];
}

__global__ __launch_bounds__(256) void k_bucket(const int* __restrict__ src,
                                                const int* __restrict__ dst,
                                                int* __restrict__ cursor,
                                                int* __restrict__ csr_src) {
    int e = blockIdx.x * 256 + threadIdx.x;
    if (e < NE) {
        int slot = atomicAdd(&cursor[dst[e]], 1);
        csr_src[slot] = src[e];
    }
}

// ---- weight transpose+convert: W[k][n] fp32 -> Wt[n][k] bf16 (k dim = F) --

__global__ __launch_bounds__(256) void k_wconv(const float* __restrict__ W,
                                               unsigned short* __restrict__ Wt,
                                               int N) {
    __shared__ float tile[32][33];
    const int n0 = blockIdx.x * 32, k0 = blockIdx.y * 32;
    const int tx = threadIdx.x & 31, ty = threadIdx.x >> 5;   // 32 x 8
#pragma unroll
    for (int i = 0; i < 32; i += 8)
        tile[ty + i][tx] = W[(size_t)(k0 + ty + i) * N + n0 + tx];  // [k][n]
    __syncthreads();
#pragma unroll
    for (int i = 0; i < 32; i += 8)
        Wt[(size_t)(n0 + ty + i) * F + k0 + tx] = f2bf(tile[tx][ty + i]);
}

// ---- h -> bf16 with norm_src fold: hb[v][f] = bf16(ns[v]*h[v][f]) ---------

__global__ __launch_bounds__(256) void k_hcvt(const float* __restrict__ h,
                                              const float* __restrict__ norm_src,
                                              unsigned short* __restrict__ hb) {
    int idx = blockIdx.x * 256 + threadIdx.x;     // NN*128 total
    int v = idx >> 7, f8 = (idx & 127) * 8;
    float ns = norm_src[v];
    const float4 a = *(const float4*)(h + (size_t)v * F + f8);
    const float4 b = *(const float4*)(h + (size_t)v * F + f8 + 4);
    ushort8v o;
    o[0] = f2bf(ns * a.x); o[1] = f2bf(ns * a.y);
    o[2] = f2bf(ns * a.z); o[3] = f2bf(ns * a.w);
    o[4] = f2bf(ns * b.x); o[5] = f2bf(ns * b.y);
    o[6] = f2bf(ns * b.z); o[7] = f2bf(ns * b.w);
    *(ushort8v*)(hb + (size_t)v * F + f8) = o;
}

// ---- aggregation: bf16 in, fp32 accumulate, bf16 out ----------------------
// XCD-partitioned: chunk c = blockIdx%8 (rides round-robin block->XCD map),
// 128 feats per chunk -> per-XCD slice 10000*128*2B = 2.56 MB < 4 MB L2.
// 16 nodes per block, 16 lanes x 8 bf16 (16B) per node. Edge loop unroll x2.
__global__ __launch_bounds__(256) void k_aggb(const unsigned short* __restrict__ xb,
                                              const int* __restrict__ row_ptr,
                                              const int* __restrict__ csr_src,
                                              unsigned short* __restrict__ aggb) {
    const int c = blockIdx.x & 7;                       // feature chunk -> XCD
    const int g = blockIdx.x >> 3;                      // node group
    const int v = g * 16 + (threadIdx.x >> 4);          // 625*16 == NN exactly
    const int f8 = c * 128 + (threadIdx.x & 15) * 8;
    const int lo = row_ptr[v], hi = row_ptr[v + 1];
    float acc[8] = {0.f, 0.f, 0.f, 0.f, 0.f, 0.f, 0.f, 0.f};
    int i = lo;
    for (; i + 2 <= hi; i += 2) {
        int s0 = csr_src[i], s1 = csr_src[i + 1];
        ushort8v x0 = *(const ushort8v*)(xb + (size_t)s0 * F + f8);
        ushort8v x1 = *(const ushort8v*)(xb + (size_t)s1 * F + f8);
#pragma unroll
        for (int j = 0; j < 8; ++j) acc[j] += bf2f(x0[j]);
#pragma unroll
        for (int j = 0; j < 8; ++j) acc[j] += bf2f(x1[j]);
    }
    if (i < hi) {
        int s = csr_src[i];
        ushort8v xv = *(const ushort8v*)(xb + (size_t)s * F + f8);
#pragma unroll
        for (int j = 0; j < 8; ++j) acc[j] += bf2f(xv[j]);
    }
    ushort8v o;
#pragma unroll
    for (int j = 0; j < 8; ++j) o[j] = f2bf(acc[j]);
    *(ushort8v*)(aggb + (size_t)v * F + f8) = o;
}

// layer-3 aggregation over z3 (fp32, 64 feats), fused nd/bias, writes d_out.
// 16 nodes per block, 16 lanes x float4 per node.
__global__ __launch_bounds__(256) void k_agg64(const float* __restrict__ z,
                                               const int* __restrict__ row_ptr,
                                               const int* __restrict__ csr_src,
                                               const float* __restrict__ norm_dst,
                                               const float* __restrict__ b3,
                                               float* __restrict__ out) {
    const int v = blockIdx.x * 16 + (threadIdx.x >> 4);
    if (v >= NN) return;
    const int f4 = (threadIdx.x & 15) * 4;
    const int lo = row_ptr[v], hi = row_ptr[v + 1];
    float4 acc = {0.f, 0.f, 0.f, 0.f};
    for (int i = lo; i < hi; ++i) {
        int s = csr_src[i];
        float4 zv = *(const float4*)(z + (size_t)s * C3 + f4);
        acc.x += zv.x; acc.y += zv.y; acc.z += zv.z; acc.w += zv.w;
    }
    float nd = norm_dst[v];
    float4 bv = *(const float4*)(b3 + f4);
    float4 o;
    o.x = acc.x * nd + bv.x; o.y = acc.y * nd + bv.y;
    o.z = acc.z * nd + bv.z; o.w = acc.w * nd + bv.w;
    *(float4*)(out + (size_t)v * C3 + f4) = o;
}

// ---- bf16 MFMA GEMM, layers 1&2: 128x128 tile, 8 waves, double-buffered ---
// Cb[m][n] = bf16( rs2[m] * relu( rs1[m]*(A@Bt^T)[m,n] + bias[n] ) )
// A: [MPAD][F] bf16. Bt: [F n][F k] bf16. Grid (79,8)=632 blocks x 512 thr.
// Wave (wm=wid&1, wn=wid>>1) computes 64x32 (mb 0..3, nb 0..1).
// Staging: wave wid stages A rows [wid*16,..+16) and B rows [wid*16,..+16):
// 1 A + 1 B gl_lds16 per thread per K-tile (2 in flight).
__global__ __launch_bounds__(512) void k_gemm_bf16(
        const unsigned short* __restrict__ A,
        const unsigned short* __restrict__ Bt,
        const float* __restrict__ bias,
        const float* __restrict__ rs1,   // norm_dst (pre-bias)
        const float* __restrict__ rs2,   // norm_src (post-relu)
        unsigned short* __restrict__ Cb) {
    __shared__ short As[2][128 * 32];
    __shared__ short Bs[2][128 * 32];
    const int t = threadIdx.x, lane = t & 63, wid = t >> 6;   // 8 waves
    const int m0 = blockIdx.x * 128, n0 = blockIdx.y * 128;
    const int wm0 = (wid & 1) * 64, wn0 = (wid >> 1) * 32;
    const int lr = lane & 15, q = lane >> 4;

    // staging: wave wid -> tile-instr wid for both A and B (16 rows each)
    const int rS  = wid * 16 + (lane >> 2);
    const int sS  = (((lane & 3) ^ ((rS >> 1) & 3)) * 8);
    const unsigned short* aSrc = A  + (size_t)(m0 + rS) * F + sS;
    const unsigned short* bSrc = Bt + (size_t)(n0 + rS) * F + sS;
    short* aDst = &As[0][wid * 512];
    short* bDst = &Bs[0][wid * 512];

    // ds_read fragment base pointers (buffer 0)
    const short* ap[4];
    const short* bp[2];
#pragma unroll
    for (int mb = 0; mb < 4; ++mb) {
        int m = wm0 + mb * 16 + lr;
        ap[mb] = &As[0][m * 32 + (q ^ ((m >> 1) & 3)) * 8];
    }
#pragma unroll
    for (int nb = 0; nb < 2; ++nb) {
        int n = wn0 + nb * 16 + lr;
        bp[nb] = &Bs[0][n * 32 + (q ^ ((n >> 1) & 3)) * 8];
    }

    floatx4 acc[4][2] = {};

    // prologue: stage tile 0 into buffer 0
    gl_lds16(aSrc, aDst);
    gl_lds16(bSrc, bDst);

    for (int kt = 0; kt < F / 32; ++kt) {
        const int buf = kt & 1;
        __syncthreads();                       // drains buf's loads (issued kt-1)
        if (kt + 1 < F / 32) {                 // prefetch next tile into other buf
            int k0 = (kt + 1) * 32;
            gl_lds16(aSrc + k0, aDst + (buf ^ 1) * (128 * 32));
            gl_lds16(bSrc + k0, bDst + (buf ^ 1) * (128 * 32));
        }
        const int bo = buf * (128 * 32);
        short8 af[4], bf[2];
#pragma unroll
        for (int mb = 0; mb < 4; ++mb) af[mb] = *(const short8*)(ap[mb] + bo);
#pragma unroll
        for (int nb = 0; nb < 2; ++nb) bf[nb] = *(const short8*)(bp[nb] + bo);
#pragma unroll
        for (int mb = 0; mb < 4; ++mb)
#pragma unroll
            for (int nb = 0; nb < 2; ++nb)
                acc[mb][nb] = __builtin_amdgcn_mfma_f32_16x16x32_bf16(
                    af[mb], bf[nb], acc[mb][nb], 0, 0, 0);
    }

    float s1[4][4], s2[4][4];
#pragma unroll
    for (int mb = 0; mb < 4; ++mb)
#pragma unroll
        for (int r = 0; r < 4; ++r) {
            int row = m0 + wm0 + mb * 16 + q * 4 + r;
            s1[mb][r] = rs1[row];
            s2[mb][r] = rs2[row];
        }
#pragma unroll
    for (int nb = 0; nb < 2; ++nb) {
        int col = n0 + wn0 + nb * 16 + lr;
        float bv = bias[col];
#pragma unroll
        for (int mb = 0; mb < 4; ++mb)
#pragma unroll
            for (int r = 0; r < 4; ++r) {
                int row = m0 + wm0 + mb * 16 + q * 4 + r;
                float v = fmaxf(acc[mb][nb][r] * s1[mb][r] + bv, 0.f) * s2[mb][r];
                Cb[(size_t)row * F + col] = f2bf(v);
            }
    }
}

// ---- bf16 MFMA GEMM, layer 3: z3 = x2' @ Wt3^T, fp32 out, N=64, dbuf ------
// BM=64, 4 waves (wave w -> rows w*16..w*16+15, cols 0..63), grid MPAD/64.
__global__ __launch_bounds__(256) void k_gemm3(
        const unsigned short* __restrict__ A,
        const unsigned short* __restrict__ Bt,   // [64 n][F k]
        float* __restrict__ Z) {
    __shared__ short As3[2][64 * 32];
    __shared__ short Bs3[2][64 * 32];
    const int t = threadIdx.x, lane = t & 63, wid = t >> 6;
    const int m0 = blockIdx.x * 64;
    const int lr = lane & 15, q = lane >> 4;

    const int r = wid * 16 + (lane >> 2);
    const int soff = (((lane & 3) ^ ((r >> 1) & 3)) * 8);
    const unsigned short* aSrc = A  + (size_t)(m0 + r) * F + soff;
    const unsigned short* bSrc = Bt + (size_t)r * F + soff;

    const short* ap;
    {
        int m = wid * 16 + lr;
        ap = &As3[0][m * 32 + (q ^ ((m >> 1) & 3)) * 8];
    }
    const short* bp[4];
#pragma unroll
    for (int nb = 0; nb < 4; ++nb) {
        int n = nb * 16 + lr;
        bp[nb] = &Bs3[0][n * 32 + (q ^ ((n >> 1) & 3)) * 8];
    }

    floatx4 acc[4] = {};

    gl_lds16(aSrc, &As3[0][wid * 512]);
    gl_lds16(bSrc, &Bs3[0][wid * 512]);

    for (int kt = 0; kt < F / 32; ++kt) {
        const int buf = kt & 1;
        __syncthreads();
        if (kt + 1 < F / 32) {
            int k0 = (kt + 1) * 32;
            gl_lds16(aSrc + k0, &As3[buf ^ 1][wid * 512]);
            gl_lds16(bSrc + k0, &Bs3[buf ^ 1][wid * 512]);
        }
        const int bo = buf * (64 * 32);
        short8 af = *(const short8*)(ap + bo);
        short8 bf[4];
#pragma unroll
        for (int nb = 0; nb < 4; ++nb) bf[nb] = *(const short8*)(bp[nb] + bo);
#pragma unroll
        for (int nb = 0; nb < 4; ++nb)
            acc[nb] = __builtin_amdgcn_mfma_f32_16x16x32_bf16(af, bf[nb], acc[nb], 0, 0, 0);
    }

#pragma unroll
    for (int nb = 0; nb < 4; ++nb) {
        int col = nb * 16 + lr;
#pragma unroll
        for (int ri = 0; ri < 4; ++ri) {
            int row = m0 + wid * 16 + q * 4 + ri;
            Z[(size_t)row * C3 + col] = acc[nb][ri];
        }
    }
}

// ---- driver ---------------------------------------------------------------

extern "C" void kernel_launch(void* const* d_in, const int* in_sizes, int n_in,
                              void* d_out, int out_size, void* d_ws, size_t ws_size,
                              hipStream_t stream) {
    const float* h   = (const float*)d_in[0];
    const int*   src = (const int*)d_in[1];
    const int*   dst = (const int*)d_in[2];
    const float* W1  = (const float*)d_in[3];
    const float* b1  = (const float*)d_in[4];
    const float* W2  = (const float*)d_in[5];
    const float* b2  = (const float*)d_in[6];
    const float* W3  = (const float*)d_in[7];
    const float* b3  = (const float*)d_in[8];
    float* out = (float*)d_out;

    char* ws = (char*)d_ws;
    int*   deg_out  = (int*)ws;                       ws += MPAD * 4;
    int*   deg_in   = (int*)ws;                       ws += MPAD * 4;
    float* norm_src = (float*)ws;                     ws += MPAD * 4;
    float* norm_dst = (float*)ws;                     ws += MPAD * 4;
    int*   row_ptr  = (int*)ws;                       ws += (NN + 1) * 4;
    int*   cursor   = (int*)ws;                       ws += NN * 4;
    int*   csr_src  = (int*)ws;                       ws += NE * 4;
    ws = (char*)(((size_t)ws + 255) & ~(size_t)255);
    unsigned short* hb   = (unsigned short*)ws;       ws += (size_t)MPAD * F * 2;
    unsigned short* aggb = (unsigned short*)ws;       ws += (size_t)MPAD * F * 2;
    unsigned short* xb   = (unsigned short*)ws;       ws += (size_t)MPAD * F * 2;
    unsigned short* Wt1  = (unsigned short*)ws;       ws += (size_t)F * F * 2;
    unsigned short* Wt2  = (unsigned short*)ws;       ws += (size_t)F * F * 2;
    unsigned short* Wt3  = (unsigned short*)ws;       ws += (size_t)C3 * F * 2;
    float* z3       = (float*)ws;                     // MPAD * C3 * 4

    // CSR build + norms + weight conversion + h conversion
    hipMemsetAsync(deg_out, 0, 2 * MPAD * sizeof(int), stream);
    k_degree<<<(NE + 255) / 256, 256, 0, stream>>>(src, dst, deg_out, deg_in);
    k_norm<<<(MPAD + 255) / 256, 256, 0, stream>>>(deg_out, deg_in, norm_src, norm_dst);
    k_scan<<<1, 1024, 0, stream>>>(deg_in, row_ptr, cursor);
    k_bucket<<<(NE + 255) / 256, 256, 0, stream>>>(src, dst, cursor, csr_src);
    k_wconv<<<dim3(F / 32, F / 32), 256, 0, stream>>>(W1, Wt1, F);
    k_wconv<<<dim3(F / 32, F / 32), 256, 0, stream>>>(W2, Wt2, F);
    k_wconv<<<dim3(C3 / 32, F / 32), 256, 0, stream>>>(W3, Wt3, C3);
    k_hcvt<<<NN * 128 / 256, 256, 0, stream>>>(h, norm_src, hb);

    // layer 1: aggb = Sum hb[src]; xb = bf16(ns.*relu(nd.*(aggb@W1)+b1))
    k_aggb<<<(NN / 16) * 8, 256, 0, stream>>>(hb, row_ptr, csr_src, aggb);
    k_gemm_bf16<<<dim3(MPAD / 128, F / 128), 512, 0, stream>>>(aggb, Wt1, b1, norm_dst, norm_src, xb);

    // layer 2
    k_aggb<<<(NN / 16) * 8, 256, 0, stream>>>(xb, row_ptr, csr_src, aggb);
    k_gemm_bf16<<<dim3(MPAD / 128, F / 128), 512, 0, stream>>>(aggb, Wt2, b2, norm_dst, norm_src, xb);

    // layer 3: z3 = xb @ W3t ; out = nd.*(A z3) + b3
    k_gemm3<<<MPAD / 64, 256, 0, stream>>>(xb, Wt3, z3);
    k_agg64<<<(NN + 15) / 16, 256, 0, stream>>>(z3, row_ptr, csr_src, norm_dst, b3, out);
}

// Round 9
// 296.892 us; speedup vs baseline: 1.1504x; 1.0266x over previous
//
#include <hip/hip_runtime.h>

// GCN: 3 x (gather-aggregate via CSR -> GEMM(+bias,+relu))
// R1: CSR gather aggregation (no fp32 atomics).
// R2: layers 1&2 GEMM -> bf16 MFMA, global_load_lds(16) staging, XOR swizzle.
// R3: bf16 end-to-end; layer-3 GEMM -> bf16 MFMA; fused epilogues.
// R4: double-buffered LDS in MFMA GEMMs; XCD-partitioned gather. (GEMM 43us)
// R5: XCD grid swizzle -> REGRESSED. R6: BN=64+vmcnt(3) -> REGRESSED
//     (time tracks staging bytes; rate plateaus ~8 TB/s for all variants).
// R7: 128x128 tile, 512-thread blocks (8 waves): GEMM ~38us. Kept.
// R8: k_aggb unroll x4 (gather is L2-latency-chain-bound; 4 loads in
//     flight); fuse 3x k_wconv into one launch; fold k_norm into k_scan
//     (15 -> 12 dispatches).
constexpr int NN   = 10000;
constexpr int NE   = 160000;
constexpr int F    = 1024;
constexpr int C3   = 64;
constexpr int MPAD = 10112;   // 79 * 128

typedef __attribute__((ext_vector_type(8))) short short8;
typedef __attribute__((ext_vector_type(8))) unsigned short ushort8v;
typedef __attribute__((ext_vector_type(4))) float floatx4;

__device__ __forceinline__ unsigned short f2bf(float f) {
    union { float f; unsigned u; } v; v.f = f;
    unsigned r = v.u + 0x7fff + ((v.u >> 16) & 1);   // RNE
    return (unsigned short)(r >> 16);
}
__device__ __forceinline__ float bf2f(unsigned short u) {
    union { unsigned u; float f; } v; v.u = ((unsigned)u) << 16;
    return v.f;
}

__device__ __forceinline__ void gl_lds16(const void* g, void* l) {
    __builtin_amdgcn_global_load_lds(
        (const __attribute__((address_space(1))) unsigned int*)g,
        (__attribute__((address_space(3))) unsigned int*)l, 16, 0, 0);
}

// ---- CSR build ------------------------------------------------------------

__global__ __launch_bounds__(256) void k_degree(const int* __restrict__ src,
                                                const int* __restrict__ dst,
                                                int* __restrict__ deg_out,
                                                int* __restrict__ deg_in) {
    int e = blockIdx.x * 256 + threadIdx.x;
    if (e < NE) {
        atomicAdd(&deg_out[src[e]], 1);
        atomicAdd(&deg_in[dst[e]], 1);
    }
}

// single-block: exclusive scan of deg_in -> row_ptr/cursor, plus both norms
// (1024 threads x CH=10 covers 10240 >= MPAD).
__global__ __launch_bounds__(1024) void k_scan(const int* __restrict__ deg_in,
                                               const int* __restrict__ deg_out,
                                               int* __restrict__ row_ptr,
                                               int* __restrict__ cursor,
                                               float* __restrict__ norm_src,
                                               float* __restrict__ norm_dst) {
    constexpr int CH = 10;
    __shared__ int sums[1024];
    const int tid = threadIdx.x;
    int local[CH];
    int tsum = 0;
#pragma unroll
    for (int j = 0; j < CH; ++j) {
        int idx = tid * CH + j;
        int v = (idx < NN) ? deg_in[idx] : 0;
        local[j] = v;
        tsum += v;
        if (idx < MPAD) {   // fused norm computation (padded rows: deg=0 -> 1.0)
            norm_src[idx] = rsqrtf(fmaxf((float)deg_out[idx], 1.0f));
            norm_dst[idx] = rsqrtf(fmaxf((float)deg_in[idx], 1.0f));
        }
    }
    sums[tid] = tsum;
    __syncthreads();
    for (int off = 1; off < 1024; off <<= 1) {
        int v = (tid >= off) ? sums[tid - off] : 0;
        __syncthreads();
        sums[tid] += v;
        __syncthreads();
    }
    int run = sums[tid] - tsum;
#pragma unroll
    for (int j = 0; j < CH; ++j) {
        int idx = tid * CH + j;
        if (idx < NN) {
            row_ptr[idx] = run;
            cursor[idx]  = run;
        }
        run += local[j];
    }
    if (tid == 1023) row_ptr[NN] = sums[1023];
}

__global__ __launch_bounds__(256) void k_bucket(const int* __restrict__ src,
                                                const int* __restrict__ dst,
                                                int* __restrict__ cursor,
                                                int* __restrict__ csr_src) {
    int e = blockIdx.x * 256 + threadIdx.x;
    if (e < NE) {
        int slot = atomicAdd(&cursor[dst[e]], 1);
        csr_src[slot] = src[e];
    }
}

// ---- fused weight transpose+convert: all three W -> Wt bf16 [n][k=F] ------
// blocks 0..1023: W1; 1024..2047: W2; 2048..2111: W3 (N=C3).
__global__ __launch_bounds__(256) void k_wconv_all(const float* __restrict__ W1,
                                                   const float* __restrict__ W2,
                                                   const float* __restrict__ W3,
                                                   unsigned short* __restrict__ Wt1,
                                                   unsigned short* __restrict__ Wt2,
                                                   unsigned short* __restrict__ Wt3) {
    __shared__ float tile[32][33];
    const float* W; unsigned short* Wt; int N, n0, k0;
    int b = blockIdx.x;
    if (b < 1024)      { W = W1; Wt = Wt1; N = F;  n0 = (b & 31) * 32;          k0 = (b >> 5) * 32; }
    else if (b < 2048) { b -= 1024; W = W2; Wt = Wt2; N = F;  n0 = (b & 31) * 32; k0 = (b >> 5) * 32; }
    else               { b -= 2048; W = W3; Wt = Wt3; N = C3; n0 = (b & 1) * 32;  k0 = (b >> 1) * 32; }
    const int tx = threadIdx.x & 31, ty = threadIdx.x >> 5;   // 32 x 8
#pragma unroll
    for (int i = 0; i < 32; i += 8)
        tile[ty + i][tx] = W[(size_t)(k0 + ty + i) * N + n0 + tx];  // [k][n]
    __syncthreads();
#pragma unroll
    for (int i = 0; i < 32; i += 8)
        Wt[(size_t)(n0 + ty + i) * F + k0 + tx] = f2bf(tile[tx][ty + i]);
}

// ---- h -> bf16 with norm_src fold: hb[v][f] = bf16(ns[v]*h[v][f]) ---------

__global__ __launch_bounds__(256) void k_hcvt(const float* __restrict__ h,
                                              const float* __restrict__ norm_src,
                                              unsigned short* __restrict__ hb) {
    int idx = blockIdx.x * 256 + threadIdx.x;     // NN*128 total
    int v = idx >> 7, f8 = (idx & 127) * 8;
    float ns = norm_src[v];
    const float4 a = *(const float4*)(h + (size_t)v * F + f8);
    const float4 b = *(const float4*)(h + (size_t)v * F + f8 + 4);
    ushort8v o;
    o[0] = f2bf(ns * a.x); o[1] = f2bf(ns * a.y);
    o[2] = f2bf(ns * a.z); o[3] = f2bf(ns * a.w);
    o[4] = f2bf(ns * b.x); o[5] = f2bf(ns * b.y);
    o[6] = f2bf(ns * b.z); o[7] = f2bf(ns * b.w);
    *(ushort8v*)(hb + (size_t)v * F + f8) = o;
}

// ---- aggregation: bf16 in, fp32 accumulate, bf16 out ----------------------
// XCD-partitioned: chunk c = blockIdx%8 -> per-XCD slice 2.56 MB < 4 MB L2.
// 16 nodes per block, 16 lanes x 8 bf16 (16B) per node. Edge loop unroll x4
// (4 independent loads in flight -- the gather is L2-latency-chain-bound).
__global__ __launch_bounds__(256) void k_aggb(const unsigned short* __restrict__ xb,
                                              const int* __restrict__ row_ptr,
                                              const int* __restrict__ csr_src,
                                              unsigned short* __restrict__ aggb) {
    const int c = blockIdx.x & 7;                       // feature chunk -> XCD
    const int g = blockIdx.x >> 3;                      // node group
    const int v = g * 16 + (threadIdx.x >> 4);          // 625*16 == NN exactly
    const int f8 = c * 128 + (threadIdx.x & 15) * 8;
    const int lo = row_ptr[v], hi = row_ptr[v + 1];
    float acc[8] = {0.f, 0.f, 0.f, 0.f, 0.f, 0.f, 0.f, 0.f};
    int i = lo;
    for (; i + 4 <= hi; i += 4) {
        int s0 = csr_src[i],     s1 = csr_src[i + 1];
        int s2 = csr_src[i + 2], s3 = csr_src[i + 3];
        ushort8v x0 = *(const ushort8v*)(xb + (size_t)s0 * F + f8);
        ushort8v x1 = *(const ushort8v*)(xb + (size_t)s1 * F + f8);
        ushort8v x2 = *(const ushort8v*)(xb + (size_t)s2 * F + f8);
        ushort8v x3 = *(const ushort8v*)(xb + (size_t)s3 * F + f8);
#pragma unroll
        for (int j = 0; j < 8; ++j) acc[j] += bf2f(x0[j]);
#pragma unroll
        for (int j = 0; j < 8; ++j) acc[j] += bf2f(x1[j]);
#pragma unroll
        for (int j = 0; j < 8; ++j) acc[j] += bf2f(x2[j]);
#pragma unroll
        for (int j = 0; j < 8; ++j) acc[j] += bf2f(x3[j]);
    }
    for (; i < hi; ++i) {
        int s = csr_src[i];
        ushort8v xv = *(const ushort8v*)(xb + (size_t)s * F + f8);
#pragma unroll
        for (int j = 0; j < 8; ++j) acc[j] += bf2f(xv[j]);
    }
    ushort8v o;
#pragma unroll
    for (int j = 0; j < 8; ++j) o[j] = f2bf(acc[j]);
    *(ushort8v*)(aggb + (size_t)v * F + f8) = o;
}

// layer-3 aggregation over z3 (fp32, 64 feats), fused nd/bias, writes d_out.
// 16 nodes per block, 16 lanes x float4 per node.
__global__ __launch_bounds__(256) void k_agg64(const float* __restrict__ z,
                                               const int* __restrict__ row_ptr,
                                               const int* __restrict__ csr_src,
                                               const float* __restrict__ norm_dst,
                                               const float* __restrict__ b3,
                                               float* __restrict__ out) {
    const int v = blockIdx.x * 16 + (threadIdx.x >> 4);
    if (v >= NN) return;
    const int f4 = (threadIdx.x & 15) * 4;
    const int lo = row_ptr[v], hi = row_ptr[v + 1];
    float4 acc = {0.f, 0.f, 0.f, 0.f};
    int i = lo;
    for (; i + 2 <= hi; i += 2) {
        int s0 = csr_src[i], s1 = csr_src[i + 1];
        float4 z0 = *(const float4*)(z + (size_t)s0 * C3 + f4);
        float4 z1 = *(const float4*)(z + (size_t)s1 * C3 + f4);
        acc.x += z0.x; acc.y += z0.y; acc.z += z0.z; acc.w += z0.w;
        acc.x += z1.x; acc.y += z1.y; acc.z += z1.z; acc.w += z1.w;
    }
    if (i < hi) {
        int s = csr_src[i];
        float4 zv = *(const float4*)(z + (size_t)s * C3 + f4);
        acc.x += zv.x; acc.y += zv.y; acc.z += zv.z; acc.w += zv.w;
    }
    float nd = norm_dst[v];
    float4 bv = *(const float4*)(b3 + f4);
    float4 o;
    o.x = acc.x * nd + bv.x; o.y = acc.y * nd + bv.y;
    o.z = acc.z * nd + bv.z; o.w = acc.w * nd + bv.w;
    *(float4*)(out + (size_t)v * C3 + f4) = o;
}

// ---- bf16 MFMA GEMM, layers 1&2: 128x128 tile, 8 waves, double-buffered ---
// Cb[m][n] = bf16( rs2[m] * relu( rs1[m]*(A@Bt^T)[m,n] + bias[n] ) )
// A: [MPAD][F] bf16. Bt: [F n][F k] bf16. Grid (79,8)=632 blocks x 512 thr.
// Wave (wm=wid&1, wn=wid>>1) computes 64x32 (mb 0..3, nb 0..1).
__global__ __launch_bounds__(512) void k_gemm_bf16(
        const unsigned short* __restrict__ A,
        const unsigned short* __restrict__ Bt,
        const float* __restrict__ bias,
        const float* __restrict__ rs1,   // norm_dst (pre-bias)
        const float* __restrict__ rs2,   // norm_src (post-relu)
        unsigned short* __restrict__ Cb) {
    __shared__ short As[2][128 * 32];
    __shared__ short Bs[2][128 * 32];
    const int t = threadIdx.x, lane = t & 63, wid = t >> 6;   // 8 waves
    const int m0 = blockIdx.x * 128, n0 = blockIdx.y * 128;
    const int wm0 = (wid & 1) * 64, wn0 = (wid >> 1) * 32;
    const int lr = lane & 15, q = lane >> 4;

    // staging: wave wid -> tile-instr wid for both A and B (16 rows each)
    const int rS  = wid * 16 + (lane >> 2);
    const int sS  = (((lane & 3) ^ ((rS >> 1) & 3)) * 8);
    const unsigned short* aSrc = A  + (size_t)(m0 + rS) * F + sS;
    const unsigned short* bSrc = Bt + (size_t)(n0 + rS) * F + sS;
    short* aDst = &As[0][wid * 512];
    short* bDst = &Bs[0][wid * 512];

    // ds_read fragment base pointers (buffer 0)
    const short* ap[4];
    const short* bp[2];
#pragma unroll
    for (int mb = 0; mb < 4; ++mb) {
        int m = wm0 + mb * 16 + lr;
        ap[mb] = &As[0][m * 32 + (q ^ ((m >> 1) & 3)) * 8];
    }
#pragma unroll
    for (int nb = 0; nb < 2; ++nb) {
        int n = wn0 + nb * 16 + lr;
        bp[nb] = &Bs[0][n * 32 + (q ^ ((n >> 1) & 3)) * 8];
    }

    floatx4 acc[4][2] = {};

    // prologue: stage tile 0 into buffer 0
    gl_lds16(aSrc, aDst);
    gl_lds16(bSrc, bDst);

    for (int kt = 0; kt < F / 32; ++kt) {
        const int buf = kt & 1;
        __syncthreads();                       // drains buf's loads (issued kt-1)
        if (kt + 1 < F / 32) {                 // prefetch next tile into other buf
            int k0 = (kt + 1) * 32;
            gl_lds16(aSrc + k0, aDst + (buf ^ 1) * (128 * 32));
            gl_lds16(bSrc + k0, bDst + (buf ^ 1) * (128 * 32));
        }
        const int bo = buf * (128 * 32);
        short8 af[4], bf[2];
#pragma unroll
        for (int mb = 0; mb < 4; ++mb) af[mb] = *(const short8*)(ap[mb] + bo);
#pragma unroll
        for (int nb = 0; nb < 2; ++nb) bf[nb] = *(const short8*)(bp[nb] + bo);
#pragma unroll
        for (int mb = 0; mb < 4; ++mb)
#pragma unroll
            for (int nb = 0; nb < 2; ++nb)
                acc[mb][nb] = __builtin_amdgcn_mfma_f32_16x16x32_bf16(
                    af[mb], bf[nb], acc[mb][nb], 0, 0, 0);
    }

    float s1[4][4], s2[4][4];
#pragma unroll
    for (int mb = 0; mb < 4; ++mb)
#pragma unroll
        for (int r = 0; r < 4; ++r) {
            int row = m0 + wm0 + mb * 16 + q * 4 + r;
            s1[mb][r] = rs1[row];
            s2[mb][r] = rs2[row];
        }
#pragma unroll
    for (int nb = 0; nb < 2; ++nb) {
        int col = n0 + wn0 + nb * 16 + lr;
        float bv = bias[col];
#pragma unroll
        for (int mb = 0; mb < 4; ++mb)
#pragma unroll
            for (int r = 0; r < 4; ++r) {
                int row = m0 + wm0 + mb * 16 + q * 4 + r;
                float v = fmaxf(acc[mb][nb][r] * s1[mb][r] + bv, 0.f) * s2[mb][r];
                Cb[(size_t)row * F + col] = f2bf(v);
            }
    }
}

// ---- bf16 MFMA GEMM, layer 3: z3 = x2' @ Wt3^T, fp32 out, N=64, dbuf ------
__global__ __launch_bounds__(256) void k_gemm3(
        const unsigned short* __restrict__ A,
        const unsigned short* __restrict__ Bt,   // [64 n][F k]
        float* __restrict__ Z) {
    __shared__ short As3[2][64 * 32];
    __shared__ short Bs3[2][64 * 32];
    const int t = threadIdx.x, lane = t & 63, wid = t >> 6;
    const int m0 = blockIdx.x * 64;
    const int lr = lane & 15, q = lane >> 4;

    const int r = wid * 16 + (lane >> 2);
    const int soff = (((lane & 3) ^ ((r >> 1) & 3)) * 8);
    const unsigned short* aSrc = A  + (size_t)(m0 + r) * F + soff;
    const unsigned short* bSrc = Bt + (size_t)r * F + soff;

    const short* ap;
    {
        int m = wid * 16 + lr;
        ap = &As3[0][m * 32 + (q ^ ((m >> 1) & 3)) * 8];
    }
    const short* bp[4];
#pragma unroll
    for (int nb = 0; nb < 4; ++nb) {
        int n = nb * 16 + lr;
        bp[nb] = &Bs3[0][n * 32 + (q ^ ((n >> 1) & 3)) * 8];
    }

    floatx4 acc[4] = {};

    gl_lds16(aSrc, &As3[0][wid * 512]);
    gl_lds16(bSrc, &Bs3[0][wid * 512]);

    for (int kt = 0; kt < F / 32; ++kt) {
        const int buf = kt & 1;
        __syncthreads();
        if (kt + 1 < F / 32) {
            int k0 = (kt + 1) * 32;
            gl_lds16(aSrc + k0, &As3[buf ^ 1][wid * 512]);
            gl_lds16(bSrc + k0, &Bs3[buf ^ 1][wid * 512]);
        }
        const int bo = buf * (64 * 32);
        short8 af = *(const short8*)(ap + bo);
        short8 bf[4];
#pragma unroll
        for (int nb = 0; nb < 4; ++nb) bf[nb] = *(const short8*)(bp[nb] + bo);
#pragma unroll
        for (int nb = 0; nb < 4; ++nb)
            acc[nb] = __builtin_amdgcn_mfma_f32_16x16x32_bf16(af, bf[nb], acc[nb], 0, 0, 0);
    }

#pragma unroll
    for (int nb = 0; nb < 4; ++nb) {
        int col = nb * 16 + lr;
#pragma unroll
        for (int ri = 0; ri < 4; ++ri) {
            int row = m0 + wid * 16 + q * 4 + ri;
            Z[(size_t)row * C3 + col] = acc[nb][ri];
        }
    }
}

// ---- driver ---------------------------------------------------------------

extern "C" void kernel_launch(void* const* d_in, const int* in_sizes, int n_in,
                              void* d_out, int out_size, void* d_ws, size_t ws_size,
                              hipStream_t stream) {
    const float* h   = (const float*)d_in[0];
    const int*   src = (const int*)d_in[1];
    const int*   dst = (const int*)d_in[2];
    const float* W1  = (const float*)d_in[3];
    const float* b1  = (const float*)d_in[4];
    const float* W2  = (const float*)d_in[5];
    const float* b2  = (const float*)d_in[6];
    const float* W3  = (const float*)d_in[7];
    const float* b3  = (const float*)d_in[8];
    float* out = (float*)d_out;

    char* ws = (char*)d_ws;
    int*   deg_out  = (int*)ws;                       ws += MPAD * 4;
    int*   deg_in   = (int*)ws;                       ws += MPAD * 4;
    float* norm_src = (float*)ws;                     ws += MPAD * 4;
    float* norm_dst = (float*)ws;                     ws += MPAD * 4;
    int*   row_ptr  = (int*)ws;                       ws += (NN + 1) * 4;
    int*   cursor   = (int*)ws;                       ws += NN * 4;
    int*   csr_src  = (int*)ws;                       ws += NE * 4;
    ws = (char*)(((size_t)ws + 255) & ~(size_t)255);
    unsigned short* hb   = (unsigned short*)ws;       ws += (size_t)MPAD * F * 2;
    unsigned short* aggb = (unsigned short*)ws;       ws += (size_t)MPAD * F * 2;
    unsigned short* xb   = (unsigned short*)ws;       ws += (size_t)MPAD * F * 2;
    unsigned short* Wt1  = (unsigned short*)ws;       ws += (size_t)F * F * 2;
    unsigned short* Wt2  = (unsigned short*)ws;       ws += (size_t)F * F * 2;
    unsigned short* Wt3  = (unsigned short*)ws;       ws += (size_t)C3 * F * 2;
    float* z3       = (float*)ws;                     // MPAD * C3 * 4

    // CSR build + norms + weight conversion + h conversion
    hipMemsetAsync(deg_out, 0, 2 * MPAD * sizeof(int), stream);
    k_degree<<<(NE + 255) / 256, 256, 0, stream>>>(src, dst, deg_out, deg_in);
    k_scan<<<1, 1024, 0, stream>>>(deg_in, deg_out, row_ptr, cursor, norm_src, norm_dst);
    k_bucket<<<(NE + 255) / 256, 256, 0, stream>>>(src, dst, cursor, csr_src);
    k_wconv_all<<<2112, 256, 0, stream>>>(W1, W2, W3, Wt1, Wt2, Wt3);
    k_hcvt<<<NN * 128 / 256, 256, 0, stream>>>(h, norm_src, hb);

    // layer 1: aggb = Sum hb[src]; xb = bf16(ns.*relu(nd.*(aggb@W1)+b1))
    k_aggb<<<(NN / 16) * 8, 256, 0, stream>>>(hb, row_ptr, csr_src, aggb);
    k_gemm_bf16<<<dim3(MPAD / 128, F / 128), 512, 0, stream>>>(aggb, Wt1, b1, norm_dst, norm_src, xb);

    // layer 2
    k_aggb<<<(NN / 16) * 8, 256, 0, stream>>>(xb, row_ptr, csr_src, aggb);
    k_gemm_bf16<<<dim3(MPAD / 128, F / 128), 512, 0, stream>>>(aggb, Wt2, b2, norm_dst, norm_src, xb);

    // layer 3: z3 = xb @ W3t ; out = nd.*(A z3) + b3
    k_gemm3<<<MPAD / 64, 256, 0, stream>>>(xb, Wt3, z3);
    k_agg64<<<(NN + 15) / 16, 256, 0, stream>>>(z3, row_ptr, csr_src, norm_dst, b3, out);
}